// Round 1
// 242.665 us; speedup vs baseline: 1.6908x; 1.6908x over previous
//
#include <hip/hip_runtime.h>

#define D 128

// ---------------- Fallback phase 1: edge scatter with atomics ----------------
__global__ __launch_bounds__(256) void k_scatter(
    const float* __restrict__ h,
    const int* __restrict__ src,
    const int* __restrict__ dst,
    const float* __restrict__ mask,
    float* __restrict__ neigh,
    long long total)
{
    long long i = (long long)blockIdx.x * blockDim.x + threadIdx.x;
    if (i >= total) return;
    int e = (int)(i >> 7);
    int d = (int)(i & 127);
    int s = src[e];
    int t = dst[e];
    float m = mask[e];
    atomicAdd(&neigh[(long long)t * D + d], h[(long long)s * D + d] * m);
}

// ---------------- Sort by dst: histogram ----------------
__global__ __launch_bounds__(256) void k_hist(
    const int* __restrict__ dst, int* cnt, int E)
{
    int e = blockIdx.x * 256 + threadIdx.x;
    if (e < E) atomicAdd(&cnt[dst[e]], 1);
}

// ---------------- Scan phase A: per-block exclusive scan + block sums ----------------
__global__ __launch_bounds__(256) void k_scanA(
    const int* __restrict__ cnt, int* rowptr, int* bsum, int N)
{
    __shared__ int tmp[256];
    const int t = threadIdx.x;
    const int i = blockIdx.x * 256 + t;
    int v = (i < N) ? cnt[i] : 0;
    tmp[t] = v;
    __syncthreads();
#pragma unroll
    for (int off = 1; off < 256; off <<= 1) {
        int y = (t >= off) ? tmp[t - off] : 0;
        __syncthreads();
        tmp[t] += y;
        __syncthreads();
    }
    if (i < N) rowptr[i] = tmp[t] - v;   // exclusive within block
    if (t == 255) bsum[blockIdx.x] = tmp[255];
}

// ---------------- Scan phase B: scan the block sums (single block, chunked) ----------------
__global__ __launch_bounds__(256) void k_scanB(int* bsum, int NB)
{
    __shared__ int tmp[256];
    const int t = threadIdx.x;
    int carry = 0;
    for (int base = 0; base < NB; base += 256) {
        int i = base + t;
        int v = (i < NB) ? bsum[i] : 0;
        tmp[t] = v;
        __syncthreads();
#pragma unroll
        for (int off = 1; off < 256; off <<= 1) {
            int y = (t >= off) ? tmp[t - off] : 0;
            __syncthreads();
            tmp[t] += y;
            __syncthreads();
        }
        int inc = tmp[t];
        if (i < NB) bsum[i] = carry + inc - v;  // exclusive + carry
        carry += tmp[255];
        __syncthreads();
    }
}

// ---------------- Scan phase C: add block offsets, emit rowptr + cursor ----------------
__global__ __launch_bounds__(256) void k_scanC(
    int* rowptr, const int* __restrict__ bsum, int* cursor, int N, int E)
{
    int i = blockIdx.x * 256 + threadIdx.x;
    if (i < N) {
        int v = rowptr[i] + bsum[i >> 8];
        rowptr[i] = v;
        cursor[i] = v;
    }
    if (i == N) rowptr[N] = E;
}

// ---------------- Reorder edges into dst-sorted (src, mask) pairs ----------------
__global__ __launch_bounds__(256) void k_reorder(
    const int* __restrict__ src, const int* __restrict__ dst,
    const float* __restrict__ mask, int* cursor,
    int2* __restrict__ es, int E)
{
    int e = blockIdx.x * 256 + threadIdx.x;
    if (e < E) {
        int t = dst[e];
        int p = atomicAdd(&cursor[t], 1);
        es[p] = make_int2(src[e], __float_as_int(mask[e]));
    }
}

// ---------------- Gather-aggregate: one wave per node, float2 per lane ----------------
// hin[n] = (1+eps)*h[n] + sum_{e: dst=n} h[src_e] * mask_e
__global__ __launch_bounds__(256) void k_gather(
    const float* __restrict__ h,
    const int* __restrict__ rowptr,
    const int2* __restrict__ es,
    const float* __restrict__ eps,
    float* __restrict__ hin, int N)
{
    int wid = blockIdx.x * 4 + (threadIdx.x >> 6);   // node index (one wave each)
    if (wid >= N) return;
    const int lane = threadIdx.x & 63;
    const int col = lane * 2;

    int jb = __builtin_amdgcn_readfirstlane(rowptr[wid]);
    int je = __builtin_amdgcn_readfirstlane(rowptr[wid + 1]);

    float ax = 0.0f, ay = 0.0f;
    int j = jb;
    for (; j + 4 <= je; j += 4) {
        int2 e0 = es[j];
        int2 e1 = es[j + 1];
        int2 e2 = es[j + 2];
        int2 e3 = es[j + 3];
        float2 v0 = *(const float2*)&h[(e0.x << 7) + col];
        float2 v1 = *(const float2*)&h[(e1.x << 7) + col];
        float2 v2 = *(const float2*)&h[(e2.x << 7) + col];
        float2 v3 = *(const float2*)&h[(e3.x << 7) + col];
        float m0 = __int_as_float(e0.y), m1 = __int_as_float(e1.y);
        float m2 = __int_as_float(e2.y), m3 = __int_as_float(e3.y);
        ax = fmaf(v0.x, m0, ax); ay = fmaf(v0.y, m0, ay);
        ax = fmaf(v1.x, m1, ax); ay = fmaf(v1.y, m1, ay);
        ax = fmaf(v2.x, m2, ax); ay = fmaf(v2.y, m2, ay);
        ax = fmaf(v3.x, m3, ax); ay = fmaf(v3.y, m3, ay);
    }
    for (; j < je; ++j) {
        int2 e0 = es[j];
        float2 v0 = *(const float2*)&h[(e0.x << 7) + col];
        float m0 = __int_as_float(e0.y);
        ax = fmaf(v0.x, m0, ax); ay = fmaf(v0.y, m0, ay);
    }

    float2 hv = *(const float2*)&h[(wid << 7) + col];
    float s1 = 1.0f + eps[0];
    float2 o;
    o.x = fmaf(s1, hv.x, ax);
    o.y = fmaf(s1, hv.y, ay);
    *(float2*)&hin[(wid << 7) + col] = o;
}

// ---------------- Dense [N,128] @ [128,128] + bias + activation ----------------
// MODE 0: in = (1+eps)*A + B, act = relu   (fallback combine path)
// MODE 1: in = A (in-place hidden), act = prelu(scal)
// MODE 2: in = A (pre-combined hin), act = relu
// 256 threads, 32 rows/block. c = tid&127, half = tid>>7 -> 16 rows/thread.
// Inner loop: k4 outer with weights held in VGPRs (amortized over 16 rows).
template <int MODE>
__global__ __launch_bounds__(256) void k_mlp(
    const float* A,
    const float* __restrict__ B,
    const float* __restrict__ W,
    const float* __restrict__ bias,
    const float* __restrict__ scal,
    float* out,
    int N)
{
    __shared__ float in_lds[32][D];
    __shared__ float Wl[64][D];

    const int tid = threadIdx.x;
    const int c = tid & 127;
    const int half = tid >> 7;
    const int row0 = blockIdx.x * 32;
    const float sc = scal[0];

    // Stage 32 input rows (1024 float4, 4 per thread).
    for (int i = tid; i < 32 * (D / 4); i += 256) {
        int r = i >> 5;
        int cc = (i & 31) * 4;
        if (row0 + r < N) {
            float4 a = *(const float4*)&A[(long long)(row0 + r) * D + cc];
            float4 v;
            if (MODE == 0) {
                float4 b4 = *(const float4*)&B[(long long)(row0 + r) * D + cc];
                float s1 = 1.0f + sc;
                v.x = fmaf(s1, a.x, b4.x);
                v.y = fmaf(s1, a.y, b4.y);
                v.z = fmaf(s1, a.z, b4.z);
                v.w = fmaf(s1, a.w, b4.w);
            } else {
                v = a;
            }
            *(float4*)&in_lds[r][cc] = v;
        }
    }

    float acc[16];
#pragma unroll
    for (int r = 0; r < 16; r++) acc[r] = 0.0f;

    for (int kc = 0; kc < 2; kc++) {
        __syncthreads();  // protect Wl (and in_lds on first iter)
        for (int i = tid; i < 64 * (D / 4); i += 256) {
            int k = i >> 5;
            int cc = (i & 31) * 4;
            *(float4*)&Wl[k][cc] =
                *(const float4*)&W[(long long)(kc * 64 + k) * D + cc];
        }
        __syncthreads();

#pragma unroll
        for (int k4 = 0; k4 < 64; k4 += 4) {
            float w0 = Wl[k4 + 0][c];
            float w1 = Wl[k4 + 1][c];
            float w2 = Wl[k4 + 2][c];
            float w3 = Wl[k4 + 3][c];
#pragma unroll
            for (int r = 0; r < 16; r++) {
                const int rr = half * 16 + r;
                float4 iv = *(const float4*)&in_lds[rr][kc * 64 + k4];
                acc[r] = fmaf(iv.x, w0, acc[r]);
                acc[r] = fmaf(iv.y, w1, acc[r]);
                acc[r] = fmaf(iv.z, w2, acc[r]);
                acc[r] = fmaf(iv.w, w3, acc[r]);
            }
        }
    }

    const float bc = bias[c];
#pragma unroll
    for (int r = 0; r < 16; r++) {
        const int rr = half * 16 + r;
        if (row0 + rr < N) {
            float v = acc[r] + bc;
            if (MODE == 1) {
                v = (v >= 0.0f) ? v : sc * v;
            } else {
                v = fmaxf(v, 0.0f);
            }
            out[(long long)(row0 + rr) * D + c] = v;
        }
    }
}

extern "C" void kernel_launch(void* const* d_in, const int* in_sizes, int n_in,
                              void* d_out, int out_size, void* d_ws, size_t ws_size,
                              hipStream_t stream)
{
    const float* h     = (const float*)d_in[0];
    // d_in[1] = snorm_n (unused by reference)
    const int*   src   = (const int*)d_in[2];
    const int*   dst   = (const int*)d_in[3];
    const float* mask  = (const float*)d_in[4];
    const float* eps   = (const float*)d_in[5];
    const float* W1    = (const float*)d_in[6];
    const float* b1    = (const float*)d_in[7];
    const float* W2    = (const float*)d_in[8];
    const float* b2    = (const float*)d_in[9];
    const float* alpha = (const float*)d_in[10];

    const int N = in_sizes[0] / D;
    const int E = in_sizes[2];
    float* out = (float*)d_out;

    const int mblocks = (N + 31) / 32;
    const int NB = (N + 255) / 256;  // scan blocks

    // Workspace layout (256B aligned)
    char* base = (char*)d_ws;
    size_t offHin = 0;
    size_t offEs  = (offHin + (size_t)N * D * 4 + 255) & ~(size_t)255;
    size_t offRp  = (offEs + (size_t)E * 8 + 255) & ~(size_t)255;
    size_t offCnt = (offRp + (size_t)(N + 1) * 4 + 255) & ~(size_t)255;
    size_t offCur = (offCnt + (size_t)N * 4 + 255) & ~(size_t)255;
    size_t offBs  = (offCur + (size_t)N * 4 + 255) & ~(size_t)255;
    size_t need   = offBs + (size_t)NB * 4;

    if (ws_size >= need) {
        // ---------- sorted-gather path (no fp32 atomics) ----------
        float* hin    = (float*)(base + offHin);
        int2*  es     = (int2*)(base + offEs);
        int*   rowptr = (int*)(base + offRp);
        int*   cnt    = (int*)(base + offCnt);
        int*   cursor = (int*)(base + offCur);
        int*   bsum   = (int*)(base + offBs);

        hipMemsetAsync(cnt, 0, (size_t)N * 4, stream);

        int eblocks = (E + 255) / 256;
        k_hist<<<eblocks, 256, 0, stream>>>(dst, cnt, E);
        k_scanA<<<NB, 256, 0, stream>>>(cnt, rowptr, bsum, N);
        k_scanB<<<1, 256, 0, stream>>>(bsum, NB);
        k_scanC<<<(N + 1 + 255) / 256, 256, 0, stream>>>(rowptr, bsum, cursor, N, E);
        k_reorder<<<eblocks, 256, 0, stream>>>(src, dst, mask, cursor, es, E);
        k_gather<<<(N + 3) / 4, 256, 0, stream>>>(h, rowptr, es, eps, hin, N);

        k_mlp<2><<<mblocks, 256, 0, stream>>>(hin, nullptr, W1, b1, eps, out, N);
        k_mlp<1><<<mblocks, 256, 0, stream>>>(out, nullptr, W2, b2, alpha, out, N);
    } else {
        // ---------- fallback: original atomic-scatter path ----------
        float* neigh = (float*)d_ws;
        hipMemsetAsync(neigh, 0, (size_t)N * D * sizeof(float), stream);
        long long total = (long long)E * D;
        int blocks = (int)((total + 255) / 256);
        k_scatter<<<blocks, 256, 0, stream>>>(h, src, dst, mask, neigh, total);
        k_mlp<0><<<mblocks, 256, 0, stream>>>(h, neigh, W1, b1, eps, out, N);
        k_mlp<1><<<mblocks, 256, 0, stream>>>(out, nullptr, W2, b2, alpha, out, N);
    }
}

// Round 2
// 164.389 us; speedup vs baseline: 2.4959x; 1.4762x over previous
//
#include <hip/hip_runtime.h>

#define D 128

// ---------------- Fallback phase 1: edge scatter with atomics ----------------
__global__ __launch_bounds__(256) void k_scatter(
    const float* __restrict__ h,
    const int* __restrict__ src,
    const int* __restrict__ dst,
    const float* __restrict__ mask,
    float* __restrict__ neigh,
    long long total)
{
    long long i = (long long)blockIdx.x * blockDim.x + threadIdx.x;
    if (i >= total) return;
    int e = (int)(i >> 7);
    int d = (int)(i & 127);
    int s = src[e];
    int t = dst[e];
    float m = mask[e];
    atomicAdd(&neigh[(long long)t * D + d], h[(long long)s * D + d] * m);
}

// ---------------- Sort by dst: histogram ----------------
__global__ __launch_bounds__(256) void k_hist(
    const int* __restrict__ dst, int* cnt, int E)
{
    int e = blockIdx.x * 256 + threadIdx.x;
    if (e < E) atomicAdd(&cnt[dst[e]], 1);
}

// ---------------- Scan phase A: per-block exclusive scan + block sums ----------------
__global__ __launch_bounds__(256) void k_scanA(
    const int* __restrict__ cnt, int* rowptr, int* bsum, int N)
{
    __shared__ int tmp[256];
    const int t = threadIdx.x;
    const int i = blockIdx.x * 256 + t;
    int v = (i < N) ? cnt[i] : 0;
    tmp[t] = v;
    __syncthreads();
#pragma unroll
    for (int off = 1; off < 256; off <<= 1) {
        int y = (t >= off) ? tmp[t - off] : 0;
        __syncthreads();
        tmp[t] += y;
        __syncthreads();
    }
    if (i < N) rowptr[i] = tmp[t] - v;   // exclusive within block
    if (t == 255) bsum[blockIdx.x] = tmp[255];
}

// ---------------- Scan phase B: scan the block sums (single block, chunked) ----------------
__global__ __launch_bounds__(256) void k_scanB(int* bsum, int NB)
{
    __shared__ int tmp[256];
    const int t = threadIdx.x;
    int carry = 0;
    for (int base = 0; base < NB; base += 256) {
        int i = base + t;
        int v = (i < NB) ? bsum[i] : 0;
        tmp[t] = v;
        __syncthreads();
#pragma unroll
        for (int off = 1; off < 256; off <<= 1) {
            int y = (t >= off) ? tmp[t - off] : 0;
            __syncthreads();
            tmp[t] += y;
            __syncthreads();
        }
        int inc = tmp[t];
        if (i < NB) bsum[i] = carry + inc - v;  // exclusive + carry
        carry += tmp[255];
        __syncthreads();
    }
}

// ---------------- Scan phase C: add block offsets, emit rowptr + cursor ----------------
__global__ __launch_bounds__(256) void k_scanC(
    int* rowptr, const int* __restrict__ bsum, int* cursor, int N, int E)
{
    int i = blockIdx.x * 256 + threadIdx.x;
    if (i < N) {
        int v = rowptr[i] + bsum[i >> 8];
        rowptr[i] = v;
        cursor[i] = v;
    }
    if (i == N) rowptr[N] = E;
}

// ---------------- Reorder edges into dst-sorted (src, mask) pairs ----------------
__global__ __launch_bounds__(256) void k_reorder(
    const int* __restrict__ src, const int* __restrict__ dst,
    const float* __restrict__ mask, int* cursor,
    int2* __restrict__ es, int E)
{
    int e = blockIdx.x * 256 + threadIdx.x;
    if (e < E) {
        int t = dst[e];
        int p = atomicAdd(&cursor[t], 1);
        es[p] = make_int2(src[e], __float_as_int(mask[e]));
    }
}

// ---------------- Gather-aggregate: one wave per node, float2 per lane ----------------
// hin[n] = (1+eps)*h[n] + sum_{e: dst=n} h[src_e] * mask_e
__global__ __launch_bounds__(256) void k_gather(
    const float* __restrict__ h,
    const int* __restrict__ rowptr,
    const int2* __restrict__ es,
    const float* __restrict__ eps,
    float* __restrict__ hin, int N)
{
    int wid = blockIdx.x * 4 + (threadIdx.x >> 6);   // node index (one wave each)
    if (wid >= N) return;
    const int lane = threadIdx.x & 63;
    const int col = lane * 2;

    int jb = __builtin_amdgcn_readfirstlane(rowptr[wid]);
    int je = __builtin_amdgcn_readfirstlane(rowptr[wid + 1]);

    float ax = 0.0f, ay = 0.0f;
    int j = jb;
    for (; j + 4 <= je; j += 4) {
        int2 e0 = es[j];
        int2 e1 = es[j + 1];
        int2 e2 = es[j + 2];
        int2 e3 = es[j + 3];
        float2 v0 = *(const float2*)&h[(e0.x << 7) + col];
        float2 v1 = *(const float2*)&h[(e1.x << 7) + col];
        float2 v2 = *(const float2*)&h[(e2.x << 7) + col];
        float2 v3 = *(const float2*)&h[(e3.x << 7) + col];
        float m0 = __int_as_float(e0.y), m1 = __int_as_float(e1.y);
        float m2 = __int_as_float(e2.y), m3 = __int_as_float(e3.y);
        ax = fmaf(v0.x, m0, ax); ay = fmaf(v0.y, m0, ay);
        ax = fmaf(v1.x, m1, ax); ay = fmaf(v1.y, m1, ay);
        ax = fmaf(v2.x, m2, ax); ay = fmaf(v2.y, m2, ay);
        ax = fmaf(v3.x, m3, ax); ay = fmaf(v3.y, m3, ay);
    }
    for (; j < je; ++j) {
        int2 e0 = es[j];
        float2 v0 = *(const float2*)&h[(e0.x << 7) + col];
        float m0 = __int_as_float(e0.y);
        ax = fmaf(v0.x, m0, ax); ay = fmaf(v0.y, m0, ay);
    }

    float2 hv = *(const float2*)&h[(wid << 7) + col];
    float s1 = 1.0f + eps[0];
    float2 o;
    o.x = fmaf(s1, hv.x, ax);
    o.y = fmaf(s1, hv.y, ay);
    *(float2*)&hin[(wid << 7) + col] = o;
}

// ---------------- Fused 2-layer MLP ----------------
// out = prelu_alpha( relu(in @ W1 + b1) @ W2 + b2 )
// COMBINE=1: in = (1+eps)*A + B (fallback path); COMBINE=0: in = A.
// 256 threads, 32 rows/block. Thread computes a 4-row x 4-col tile:
//   cg = (tid&31)*4 (columns), rg = (tid>>5)*4 (rows).
// W staged in 32-row LDS chunks (16KB); input rows in LDS (16KB) -> 32KB/block.
// Per k4-group: 4 float4 W reads + 4 broadcast float4 input reads per 64 FMAs.
__device__ __forceinline__ void mlp_compute(
    const float in_lds[32][D], float Wl[32][D], const float* __restrict__ W,
    int tid, int cg, int rg, float4 acc[4])
{
    acc[0] = make_float4(0.f, 0.f, 0.f, 0.f);
    acc[1] = make_float4(0.f, 0.f, 0.f, 0.f);
    acc[2] = make_float4(0.f, 0.f, 0.f, 0.f);
    acc[3] = make_float4(0.f, 0.f, 0.f, 0.f);

    for (int kc = 0; kc < 4; kc++) {
        __syncthreads();   // Wl free to overwrite (and in_lds ready on first pass)
        for (int i = tid; i < 32 * (D / 4); i += 256) {
            int k = i >> 5;
            int cc = (i & 31) * 4;
            *(float4*)&Wl[k][cc] = *(const float4*)&W[(kc * 32 + k) * D + cc];
        }
        __syncthreads();

        const int kb = kc * 32;
#pragma unroll
        for (int k4 = 0; k4 < 32; k4 += 4) {
            float4 w0 = *(const float4*)&Wl[k4 + 0][cg];
            float4 w1 = *(const float4*)&Wl[k4 + 1][cg];
            float4 w2 = *(const float4*)&Wl[k4 + 2][cg];
            float4 w3 = *(const float4*)&Wl[k4 + 3][cg];
#pragma unroll
            for (int r = 0; r < 4; r++) {
                float4 iv = *(const float4*)&in_lds[rg + r][kb + k4];
                acc[r].x = fmaf(iv.x, w0.x, acc[r].x);
                acc[r].y = fmaf(iv.x, w0.y, acc[r].y);
                acc[r].z = fmaf(iv.x, w0.z, acc[r].z);
                acc[r].w = fmaf(iv.x, w0.w, acc[r].w);
                acc[r].x = fmaf(iv.y, w1.x, acc[r].x);
                acc[r].y = fmaf(iv.y, w1.y, acc[r].y);
                acc[r].z = fmaf(iv.y, w1.z, acc[r].z);
                acc[r].w = fmaf(iv.y, w1.w, acc[r].w);
                acc[r].x = fmaf(iv.z, w2.x, acc[r].x);
                acc[r].y = fmaf(iv.z, w2.y, acc[r].y);
                acc[r].z = fmaf(iv.z, w2.z, acc[r].z);
                acc[r].w = fmaf(iv.z, w2.w, acc[r].w);
                acc[r].x = fmaf(iv.w, w3.x, acc[r].x);
                acc[r].y = fmaf(iv.w, w3.y, acc[r].y);
                acc[r].z = fmaf(iv.w, w3.z, acc[r].z);
                acc[r].w = fmaf(iv.w, w3.w, acc[r].w);
            }
        }
    }
}

template <int COMBINE>
__global__ __launch_bounds__(256) void k_mlp2(
    const float* __restrict__ A,
    const float* __restrict__ B,
    const float* __restrict__ W1,
    const float* __restrict__ b1,
    const float* __restrict__ W2,
    const float* __restrict__ b2,
    const float* __restrict__ eps,
    const float* __restrict__ alpha,
    float* __restrict__ out,
    int N)
{
    __shared__ float in_lds[32][D];
    __shared__ float Wl[32][D];

    const int tid = threadIdx.x;
    const int cg = (tid & 31) * 4;
    const int rg = (tid >> 5) * 4;
    const int row0 = blockIdx.x * 32;

    // Stage 32 input rows.
    {
        const float s1 = COMBINE ? (1.0f + eps[0]) : 0.0f;
        for (int i = tid; i < 32 * (D / 4); i += 256) {
            int r = i >> 5;
            int cc = (i & 31) * 4;
            float4 v = make_float4(0.f, 0.f, 0.f, 0.f);
            if (row0 + r < N) {
                float4 a = *(const float4*)&A[(long long)(row0 + r) * D + cc];
                if (COMBINE) {
                    float4 b4 = *(const float4*)&B[(long long)(row0 + r) * D + cc];
                    v.x = fmaf(s1, a.x, b4.x);
                    v.y = fmaf(s1, a.y, b4.y);
                    v.z = fmaf(s1, a.z, b4.z);
                    v.w = fmaf(s1, a.w, b4.w);
                } else {
                    v = a;
                }
            }
            *(float4*)&in_lds[r][cc] = v;
        }
    }

    float4 acc[4];

    // ---- layer 1 ----
    mlp_compute(in_lds, Wl, W1, tid, cg, rg, acc);

    // relu(acc + b1) -> hidden back into in_lds
    __syncthreads();   // everyone done reading in_lds
    {
        float4 bb = *(const float4*)&b1[cg];
#pragma unroll
        for (int r = 0; r < 4; r++) {
            float4 v;
            v.x = fmaxf(acc[r].x + bb.x, 0.0f);
            v.y = fmaxf(acc[r].y + bb.y, 0.0f);
            v.z = fmaxf(acc[r].z + bb.z, 0.0f);
            v.w = fmaxf(acc[r].w + bb.w, 0.0f);
            *(float4*)&in_lds[rg + r][cg] = v;
        }
    }
    // (visibility of hidden writes guaranteed by the leading sync in mlp_compute)

    // ---- layer 2 ----
    mlp_compute(in_lds, Wl, W2, tid, cg, rg, acc);

    // prelu(acc + b2) -> out
    {
        float4 bb = *(const float4*)&b2[cg];
        const float al = alpha[0];
#pragma unroll
        for (int r = 0; r < 4; r++) {
            int row = row0 + rg + r;
            if (row < N) {
                float4 v;
                v.x = acc[r].x + bb.x; v.x = (v.x >= 0.0f) ? v.x : al * v.x;
                v.y = acc[r].y + bb.y; v.y = (v.y >= 0.0f) ? v.y : al * v.y;
                v.z = acc[r].z + bb.z; v.z = (v.z >= 0.0f) ? v.z : al * v.z;
                v.w = acc[r].w + bb.w; v.w = (v.w >= 0.0f) ? v.w : al * v.w;
                *(float4*)&out[(long long)row * D + cg] = v;
            }
        }
    }
}

extern "C" void kernel_launch(void* const* d_in, const int* in_sizes, int n_in,
                              void* d_out, int out_size, void* d_ws, size_t ws_size,
                              hipStream_t stream)
{
    const float* h     = (const float*)d_in[0];
    // d_in[1] = snorm_n (unused by reference)
    const int*   src   = (const int*)d_in[2];
    const int*   dst   = (const int*)d_in[3];
    const float* mask  = (const float*)d_in[4];
    const float* eps   = (const float*)d_in[5];
    const float* W1    = (const float*)d_in[6];
    const float* b1    = (const float*)d_in[7];
    const float* W2    = (const float*)d_in[8];
    const float* b2    = (const float*)d_in[9];
    const float* alpha = (const float*)d_in[10];

    const int N = in_sizes[0] / D;
    const int E = in_sizes[2];
    float* out = (float*)d_out;

    const int mblocks = (N + 31) / 32;
    const int NB = (N + 255) / 256;  // scan blocks

    // Workspace layout (256B aligned)
    char* base = (char*)d_ws;
    size_t offHin = 0;
    size_t offEs  = (offHin + (size_t)N * D * 4 + 255) & ~(size_t)255;
    size_t offRp  = (offEs + (size_t)E * 8 + 255) & ~(size_t)255;
    size_t offCnt = (offRp + (size_t)(N + 1) * 4 + 255) & ~(size_t)255;
    size_t offCur = (offCnt + (size_t)N * 4 + 255) & ~(size_t)255;
    size_t offBs  = (offCur + (size_t)N * 4 + 255) & ~(size_t)255;
    size_t need   = offBs + (size_t)NB * 4;

    if (ws_size >= need) {
        // ---------- sorted-gather path (no fp32 atomics) ----------
        float* hin    = (float*)(base + offHin);
        int2*  es     = (int2*)(base + offEs);
        int*   rowptr = (int*)(base + offRp);
        int*   cnt    = (int*)(base + offCnt);
        int*   cursor = (int*)(base + offCur);
        int*   bsum   = (int*)(base + offBs);

        hipMemsetAsync(cnt, 0, (size_t)N * 4, stream);

        int eblocks = (E + 255) / 256;
        k_hist<<<eblocks, 256, 0, stream>>>(dst, cnt, E);
        k_scanA<<<NB, 256, 0, stream>>>(cnt, rowptr, bsum, N);
        k_scanB<<<1, 256, 0, stream>>>(bsum, NB);
        k_scanC<<<(N + 1 + 255) / 256, 256, 0, stream>>>(rowptr, bsum, cursor, N, E);
        k_reorder<<<eblocks, 256, 0, stream>>>(src, dst, mask, cursor, es, E);
        k_gather<<<(N + 3) / 4, 256, 0, stream>>>(h, rowptr, es, eps, hin, N);

        k_mlp2<0><<<mblocks, 256, 0, stream>>>(hin, nullptr, W1, b1, W2, b2,
                                               eps, alpha, out, N);
    } else {
        // ---------- fallback: atomic-scatter path ----------
        float* neigh = (float*)d_ws;
        hipMemsetAsync(neigh, 0, (size_t)N * D * sizeof(float), stream);
        long long total = (long long)E * D;
        int blocks = (int)((total + 255) / 256);
        k_scatter<<<blocks, 256, 0, stream>>>(h, src, dst, mask, neigh, total);
        k_mlp2<1><<<mblocks, 256, 0, stream>>>(h, neigh, W1, b1, W2, b2,
                                               eps, alpha, out, N);
    }
}